// Round 9
// baseline (117.613 us; speedup 1.0000x reference)
//
#include <hip/hip_runtime.h>

#define E_ 32640

typedef __bf16 bf16x8 __attribute__((ext_vector_type(8)));
typedef float f32x4 __attribute__((ext_vector_type(4)));

__device__ __forceinline__ unsigned short cvt1(float f) {
  return __builtin_bit_cast(unsigned short, (__bf16)f);
}

// Swizzled LDS helpers: row-major bf16, byte ^= (row&7)<<4
__device__ __forceinline__ bf16x8 ldfrag(const unsigned short* base, int row, int kbyte, int rowbytes) {
  int byte = (row * rowbytes + kbyte) ^ ((row & 7) << 4);
  return *reinterpret_cast<const bf16x8*>(reinterpret_cast<const char*>(base) + byte);
}
__device__ __forceinline__ void st2(unsigned short* base, int row, int colbyte, int rowbytes, unsigned short v) {
  int byte = (row * rowbytes + colbyte) ^ ((row & 7) << 4);
  *reinterpret_cast<unsigned short*>(reinterpret_cast<char*>(base) + byte) = v;
}
__device__ __forceinline__ bf16x8 pack8(float4 lo, float4 hi) {
  bf16x8 r;
  r[0] = (__bf16)lo.x; r[1] = (__bf16)lo.y; r[2] = (__bf16)lo.z; r[3] = (__bf16)lo.w;
  r[4] = (__bf16)hi.x; r[5] = (__bf16)hi.y; r[6] = (__bf16)hi.z; r[7] = (__bf16)hi.w;
  return r;
}
__device__ __forceinline__ int ubase(int i) { return (i * (511 - i)) >> 1; }

// 16-row 3-plane store (planes +8192/+16384 B)
__device__ __forceinline__ void stA3(unsigned short* sA0, int lr, int cb, float4 v) {
  int byte = (lr * 512 + cb) ^ ((lr & 7) << 4);
  char* p = reinterpret_cast<char*>(sA0) + byte;
  *reinterpret_cast<unsigned short*>(p)         = cvt1(v.y);
  *reinterpret_cast<unsigned short*>(p + 8192)  = cvt1(v.z);
  *reinterpret_cast<unsigned short*>(p + 16384) = cvt1(v.w);
}

// ======== stage1: scatter 16-row stripe + GEMM1 + GEMM2 -> M[b][256][64] f32 ========
// 4096 blocks = (batch, stripe 0..15), 512 threads.
__global__ __launch_bounds__(512, 4) void stage1_kernel(
    const float* __restrict__ se_g,
    const float* __restrict__ w1,  const float* __restrict__ b1,
    const float* __restrict__ w2,  const float* __restrict__ b2,
    float* __restrict__ Mg)
{
  __shared__ __align__(16) unsigned short sA[3 * 16 * 256];   // 24 KB, rowbytes 512
  __shared__ __align__(16) unsigned short sH3[3 * 16 * 128];  // 12 KB, rowbytes 256

  const int tid = threadIdx.x;
  const int i   = blockIdx.x;
  const int batch  = (i & 7) * 32 + ((i >> 3) & 31);   // XCD-grouped batches
  const int stripe = i >> 8;                            // 0..15
  const int r0     = stripe * 16;

  const int w   = tid >> 6;   // wave 0..7
  const int l   = tid & 63;
  const int l15 = l & 15;
  const int lk  = l >> 4;
  const int kb0 = lk * 16;

  const float4* seB = reinterpret_cast<const float4*>(se_g) + (size_t)batch * E_;

  // ================= ISSUE all 16 independent loads =================
  // upper: contiguous span of rows [r0, r0+16), S <= 3960 <= 8*512
  const int s0 = ubase(r0);
  const int S  = ubase(r0 + 16) - s0;
  float4 pf[8];
  #pragma unroll
  for (int k = 0; k < 8; ++k) {
    int t = tid + k * 512;
    pf[k] = seB[s0 + (t < S ? t : 0)];
  }
  // lower: rows j < r0, 2 threads per row, 8 contiguous edges each (cols r0+8h..)
  const bool hasL = tid < 2 * r0;
  const int  j_l  = tid >> 1;
  const int  h_l  = tid & 1;
  const int  u_l  = j_l * 255 - ((j_l * (j_l - 1)) >> 1) + (r0 - j_l - 1) + 8 * h_l;
  float4 lv[8];
  #pragma unroll
  for (int k = 0; k < 8; ++k)
    lv[k] = seB[hasL ? u_l + k : 0];

  // Pin the schedule: nothing may cross — all 16 loads stay issued-ahead.
  __builtin_amdgcn_sched_barrier(0);

  // ================= CONSUME =================
  // upper: branchless decode (exact single-step +/-1 fixup), store + in-stripe mirror
  #pragma unroll
  for (int k = 0; k < 8; ++k) {
    int t = tid + k * 512;
    int g = s0 + t;
    g = g < (E_ - 1) ? g : (E_ - 1);               // keep disc >= 0 for dead lanes
    float disc = (float)(261121 - 8 * g);
    int gi = (int)((511.0f - sqrtf(disc)) * 0.5f);
    gi -= (gi * (511 - gi) > 2 * g) ? 1 : 0;
    gi += (((gi + 1) * (510 - gi)) <= 2 * g) ? 1 : 0;
    int j = g - ((gi * (511 - gi)) >> 1) + gi + 1;
    if (t < S) {
      stA3(sA, gi - r0, j * 2, pf[k]);
      if (j < r0 + 16) stA3(sA, j - r0, gi * 2, pf[k]);  // mirror inside stripe
    }
  }
  // lower (no decode needed): tile row = 8*h_l+k, col = j_l
  if (hasL) {
    #pragma unroll
    for (int k = 0; k < 8; ++k)
      stA3(sA, 8 * h_l + k, j_l * 2, lv[k]);
  }
  // diagonal = 0
  if (tid < 16) {
    int byte = (tid * 512 + (r0 + tid) * 2) ^ ((tid & 7) << 4);
    char* p = reinterpret_cast<char*>(sA) + byte;
    *reinterpret_cast<unsigned short*>(p)         = 0;
    *reinterpret_cast<unsigned short*>(p + 8192)  = 0;
    *reinterpret_cast<unsigned short*>(p + 16384) = 0;
  }
  __syncthreads();   // A staged

  // ---- weights AFTER staging (pf/lv dead -> pressure isolated) ----
  bf16x8 W1f[8];
  {
    const float* p = w1 + (w * 16 + l15) * 256 + lk * 8;   // col-tile = wave
    #pragma unroll
    for (int ks = 0; ks < 8; ++ks)
      W1f[ks] = pack8(*reinterpret_cast<const float4*>(p + ks * 32),
                      *reinterpret_cast<const float4*>(p + ks * 32 + 4));
  }
  const float b1v = b1[w * 16 + l15];

  // ---- GEMM1: H3[e][16][128] = relu(A_e @ W1^T + b1) ----
  #pragma unroll
  for (int e = 0; e < 3; ++e) {
    f32x4 acc = {0, 0, 0, 0};
    const unsigned short* sAe = sA + e * 4096;   // 8192 B per plane
    #pragma unroll
    for (int ks = 0; ks < 8; ++ks)
      acc = __builtin_amdgcn_mfma_f32_16x16x32_bf16(
          ldfrag(sAe, l15, ks * 64 + kb0, 512), W1f[ks], acc, 0, 0, 0);
    unsigned short* sHe = sH3 + e * 2048;
    int cc = w * 16 + l15;
    #pragma unroll
    for (int r = 0; r < 4; ++r)
      st2(sHe, lk * 4 + r, cc * 2, 256, cvt1(fmaxf(acc[r] + b1v, 0.f)));
  }
  __syncthreads();   // H ready

  // ---- GEMM2 (waves 0-3): M[16][64] = sum_e wte*relu(H_e @ W2^T + b2) -> global ----
  if (w < 4) {
    bf16x8 W2f[4];
    {
      const float* p = w2 + (w * 16 + l15) * 128 + lk * 8;
      #pragma unroll
      for (int ks = 0; ks < 4; ++ks)
        W2f[ks] = pack8(*reinterpret_cast<const float4*>(p + ks * 32),
                        *reinterpret_cast<const float4*>(p + ks * 32 + 4));
    }
    const float b2v = b2[w * 16 + l15];
    f32x4 osum = {0, 0, 0, 0};
    #pragma unroll
    for (int e = 0; e < 3; ++e) {
      f32x4 acc = {0, 0, 0, 0};
      const unsigned short* sHe = sH3 + e * 2048;
      #pragma unroll
      for (int ks = 0; ks < 4; ++ks)
        acc = __builtin_amdgcn_mfma_f32_16x16x32_bf16(
            ldfrag(sHe, l15, ks * 64 + kb0, 256), W2f[ks], acc, 0, 0, 0);
      float wte = 0.2f * (float)(e + 1);
      #pragma unroll
      for (int r = 0; r < 4; ++r)
        osum[r] += wte * fmaxf(acc[r] + b2v, 0.f);
    }
    #pragma unroll
    for (int r = 0; r < 4; ++r)
      Mg[((size_t)batch * 256 + r0 + lk * 4 + r) * 64 + w * 16 + l15] = osum[r];
  }
}

// ======== head: per batch, M[256][64] -> P1 -> P2 -> rowsum -> mean -> 64->2 ========
__global__ __launch_bounds__(512) void head_kernel(
    const float* __restrict__ Mg,
    const float* __restrict__ wo1, const float* __restrict__ bo1,
    const float* __restrict__ wo2, const float* __restrict__ bo2,
    const float* __restrict__ wo3, const float* __restrict__ bo3,
    float* __restrict__ out)
{
  __shared__ __align__(16) unsigned short sX[32 * 64];  // 4 KB, rowbytes 128
  __shared__ __align__(16) unsigned short sP[32 * 64];  // 4 KB
  __shared__ float sAccW[8][64];
  __shared__ float sMean[64];

  const int tid = threadIdx.x;
  const int b   = blockIdx.x;
  const int w   = tid >> 6;
  const int l   = tid & 63;
  const int l15 = l & 15;
  const int lk  = l >> 4;
  const int kb0 = lk * 16;
  const int r2  = w >> 2;   // rowtile of 32-row chunk
  const int c2  = w & 3;    // coltile

  reinterpret_cast<float*>(sAccW)[tid] = 0.f;  // wave-private rows -> no hazard

  bf16x8 WO1f[2], WO2f[2];
  {
    const float* q1 = wo1 + (c2 * 16 + l15) * 64 + lk * 8;
    const float* q2 = wo2 + (c2 * 16 + l15) * 64 + lk * 8;
    #pragma unroll
    for (int ks = 0; ks < 2; ++ks) {
      WO1f[ks] = pack8(*reinterpret_cast<const float4*>(q1 + ks * 32),
                       *reinterpret_cast<const float4*>(q1 + ks * 32 + 4));
      WO2f[ks] = pack8(*reinterpret_cast<const float4*>(q2 + ks * 32),
                       *reinterpret_cast<const float4*>(q2 + ks * 32 + 4));
    }
  }
  const float bo1v = bo1[c2 * 16 + l15];
  const float bo2v = bo2[c2 * 16 + l15];

  const int xr = tid >> 4;          // staging row 0..31
  const int xc = (tid & 15) * 4;    // staging col (4 floats)
  const float* Mb = Mg + (size_t)b * 256 * 64;

  float4 nv = *reinterpret_cast<const float4*>(Mb + xr * 64 + xc);  // chunk 0

  for (int ch = 0; ch < 8; ++ch) {
    // write staged chunk (cvt f32->bf16, swizzled)
    {
      unsigned p01 = ((unsigned)cvt1(nv.y) << 16) | cvt1(nv.x);
      unsigned p23 = ((unsigned)cvt1(nv.w) << 16) | cvt1(nv.z);
      int byte = (xr * 128 + xc * 2) ^ ((xr & 7) << 4);
      uint2 u = make_uint2(p01, p23);
      *reinterpret_cast<uint2*>(reinterpret_cast<char*>(sX) + byte) = u;
    }
    __syncthreads();   // X ready
    if (ch < 7)        // prefetch next chunk; latency hides under P1/P2
      nv = *reinterpret_cast<const float4*>(Mb + ((ch + 1) * 32 + xr) * 64 + xc);

    // P1 = relu(X @ WO1^T + bo1)
    {
      f32x4 acc = {0, 0, 0, 0};
      int arow = r2 * 16 + l15;
      #pragma unroll
      for (int ks = 0; ks < 2; ++ks)
        acc = __builtin_amdgcn_mfma_f32_16x16x32_bf16(
            ldfrag(sX, arow, ks * 64 + kb0, 128), WO1f[ks], acc, 0, 0, 0);
      #pragma unroll
      for (int r = 0; r < 4; ++r)
        st2(sP, r2 * 16 + lk * 4 + r, (c2 * 16 + l15) * 2, 128, cvt1(fmaxf(acc[r] + bo1v, 0.f)));
    }
    __syncthreads();   // P ready
    // P2 + rowsum accumulate
    {
      f32x4 acc = {0, 0, 0, 0};
      int arow = r2 * 16 + l15;
      #pragma unroll
      for (int ks = 0; ks < 2; ++ks)
        acc = __builtin_amdgcn_mfma_f32_16x16x32_bf16(
            ldfrag(sP, arow, ks * 64 + kb0, 128), WO2f[ks], acc, 0, 0, 0);
      float s = 0.f;
      #pragma unroll
      for (int r = 0; r < 4; ++r) s += fmaxf(acc[r] + bo2v, 0.f);
      s += __shfl_xor(s, 16);
      s += __shfl_xor(s, 32);
      if (lk == 0) sAccW[w][c2 * 16 + l15] += s;
    }
    __syncthreads();   // sX safe to overwrite (P1 done), sAccW settled
  }

  if (tid < 64) {
    float s = 0.f;
    #pragma unroll
    for (int ww = 0; ww < 8; ++ww) s += sAccW[ww][tid];
    sMean[tid] = s * (1.0f / 256.0f);
  }
  __syncthreads();
  if (tid < 128) {
    int c = tid >> 6;
    float v = sMean[l] * wo3[c * 64 + l];
    #pragma unroll
    for (int off = 32; off > 0; off >>= 1) v += __shfl_down(v, off);
    if (l == 0) out[b * 2 + c] = v + bo3[c];
  }
}

extern "C" void kernel_launch(void* const* d_in, const int* in_sizes, int n_in,
                              void* d_out, int out_size, void* d_ws, size_t ws_size,
                              hipStream_t stream) {
  (void)in_sizes; (void)n_in; (void)ws_size; (void)out_size;
  const float* se  = (const float*)d_in[1];   // d_in[0] = `inputs` — shape-only, never read
  const float* w1  = (const float*)d_in[2];
  const float* b1  = (const float*)d_in[3];
  const float* w2  = (const float*)d_in[4];
  const float* b2  = (const float*)d_in[5];
  const float* wo1 = (const float*)d_in[6];
  const float* bo1 = (const float*)d_in[7];
  const float* wo2 = (const float*)d_in[8];
  const float* bo2 = (const float*)d_in[9];
  const float* wo3 = (const float*)d_in[10];
  const float* bo3 = (const float*)d_in[11];

  float* Mg = (float*)d_ws;   // 256*256*64 f32 = 16.78 MB
  stage1_kernel<<<dim3(4096), dim3(512), 0, stream>>>(se, w1, b1, w2, b2, Mg);
  head_kernel<<<dim3(256), dim3(512), 0, stream>>>(Mg, wo1, bo1, wo2, bo2, wo3, bo3, (float*)d_out);
}